// Round 1
// baseline (732.606 us; speedup 1.0000x reference)
//
#include <hip/hip_runtime.h>
#include <hip/hip_bf16.h>

// MoCo loss on MI355X. V=2, N=1024, D=128, K=65536, fp32 in, 2 fp32 scalars out.
//
// loss1 = (1/(V*N)) * sum_{x,i} (2 - 2*q[x,i]·k[1-x,i])          (softmax over 1 elem == 1)
// loss2 = -(1/(V*N)) * sum_{x,i} num[x,i]/den[x,i]
//   den[x,i] = sum_j exp(-qdq[i,j]) + sum_{j!=i} exp(-intra_x[i,j])
//   num[x,i] = sum_j qdq*exp(-qdq)  + sum_{j!=i} intra*exp(-intra)
//   qdq[i,j]   = 2 - 2*(q[0,i]·queue[:,j])   (q[0] for BOTH views — reference memoization)
//   intra_x[i,j] = 2 - 2*(q[x,i]·q[x,j])     (rows are L2-normalized)
//
// ws layout (floats):
//   [0,1024)    QS_e      queue-part sum exp(-c), per row i (shared across views)
//   [1024,2048) QS_ce     queue-part sum c*exp(-c)
//   [2048,4096) IS_e[2][1024]   intra-part per view
//   [4096,6144) IS_ce[2][1024]
//   [6144]      l1acc
//   [8192, 8192+2*128*1024)  qT[x][d][i]  (q transposed so intra can use
//                            the same coalesced column kernel as queue)
// total ~1.06 MB.

#define NROWS 1024
#define DDIM  128
#define KQ    65536
#define RB    32   // rows per block in colreduce

__device__ __forceinline__ float wave_sum(float v) {
  #pragma unroll
  for (int o = 32; o > 0; o >>= 1) v += __shfl_down(v, o, 64);
  return v;
}

__global__ void zero_ws(float* __restrict__ ws) {
  ws[blockIdx.x * 256 + threadIdx.x] = 0.f;
}

// qT[x][d][i] = q[x][i][d]
__global__ void transpose_q(const float* __restrict__ q, float* __restrict__ qT) {
  int idx = blockIdx.x * 256 + threadIdx.x;    // [0, 2*1024*128)
  int x   = idx >> 17;
  int rem = idx & 131071;
  int i   = rem >> 7;
  int d   = rem & 127;
  qT[x * 131072 + d * 1024 + i] = q[idx];
}

// Fused GEMV-panel + exp reduction.
// Qrows: [>=r0+RB][128] row-major (wave-uniform reads -> scalar loads).
// Cols : [128][M] (column j contiguous across lanes -> coalesced).
// Accumulates per-row sum(exp(-c)) and sum(c*exp(-c)), c = 2 - 2*dot.
// excludeDiag=1 skips j == global row index (intra diagonal).
__global__ void colreduce(const float* __restrict__ Qrows,
                          const float* __restrict__ Cols,
                          int M, int colsPerChunk,
                          float* __restrict__ acc_e,
                          float* __restrict__ acc_ce,
                          int excludeDiag) {
  const int r0    = blockIdx.x * RB;
  const int cbase = blockIdx.y * colsPerChunk;

  float th_e[RB], th_ce[RB];
  #pragma unroll
  for (int r = 0; r < RB; ++r) { th_e[r] = 0.f; th_ce[r] = 0.f; }

  for (int j = cbase + (int)threadIdx.x; j < cbase + colsPerChunk; j += blockDim.x) {
    float dot[RB];
    #pragma unroll
    for (int r = 0; r < RB; ++r) dot[r] = 0.f;

    const float* cp = Cols + j;
    for (int d = 0; d < DDIM; d += 4) {
      float cv0 = cp[(size_t)(d + 0) * M];
      float cv1 = cp[(size_t)(d + 1) * M];
      float cv2 = cp[(size_t)(d + 2) * M];
      float cv3 = cp[(size_t)(d + 3) * M];
      #pragma unroll
      for (int r = 0; r < RB; ++r) {
        const float* qp = Qrows + (size_t)(r0 + r) * DDIM + d;  // wave-uniform
        dot[r] = fmaf(qp[0], cv0,
                 fmaf(qp[1], cv1,
                 fmaf(qp[2], cv2,
                 fmaf(qp[3], cv3, dot[r]))));
      }
    }

    #pragma unroll
    for (int r = 0; r < RB; ++r) {
      float c = 2.f - 2.f * dot[r];
      float e = __expf(-c);
      bool skip = (excludeDiag != 0) && (j == r0 + r);
      if (!skip) { th_e[r] += e; th_ce[r] += c * e; }
    }
  }

  const int lane = (int)threadIdx.x & 63;
  #pragma unroll
  for (int r = 0; r < RB; ++r) {
    float e  = wave_sum(th_e[r]);
    float ce = wave_sum(th_ce[r]);
    if (lane == 0) {
      atomicAdd(&acc_e[r0 + r], e);
      atomicAdd(&acc_ce[r0 + r], ce);
    }
  }
}

// loss1: one wave per (x,i); lane holds 2 of the 128 dims.
__global__ void loss1_k(const float* __restrict__ q, const float* __restrict__ k,
                        float* __restrict__ l1acc) {
  int gw   = (int)(blockIdx.x * blockDim.x + threadIdx.x) >> 6;   // 0..2047
  int lane = (int)threadIdx.x & 63;
  int x = gw >> 10;
  int i = gw & 1023;
  const float2* qp = (const float2*)(q + (size_t)(x * NROWS + i) * DDIM);
  const float2* kp = (const float2*)(k + (size_t)((1 - x) * NROWS + i) * DDIM);
  float2 a = qp[lane];
  float2 b = kp[lane];
  float s = wave_sum(a.x * b.x + a.y * b.y);
  if (lane == 0) atomicAdd(l1acc, (2.f - 2.f * s) * (1.f / (2.f * NROWS)));
}

__global__ void final_k(const float* __restrict__ ws, float* __restrict__ out) {
  const float* QS_e  = ws;
  const float* QS_ce = ws + 1024;
  const float* IS_e  = ws + 2048;
  const float* IS_ce = ws + 4096;
  const float* l1    = ws + 6144;
  __shared__ float red[256];
  float part = 0.f;
  for (int idx = (int)threadIdx.x; idx < 2048; idx += 256) {
    int x = idx >> 10;
    int i = idx & 1023;
    float den = QS_e[i] + IS_e[x * 1024 + i];
    float num = QS_ce[i] + IS_ce[x * 1024 + i];
    part += num / den;
  }
  red[threadIdx.x] = part;
  __syncthreads();
  for (int s = 128; s > 0; s >>= 1) {
    if ((int)threadIdx.x < s) red[threadIdx.x] += red[threadIdx.x + s];
    __syncthreads();
  }
  if (threadIdx.x == 0) {
    out[0] = l1[0];
    out[1] = -red[0] * (1.f / (2.f * NROWS));
  }
}

extern "C" void kernel_launch(void* const* d_in, const int* in_sizes, int n_in,
                              void* d_out, int out_size, void* d_ws, size_t ws_size,
                              hipStream_t stream) {
  const float* q     = (const float*)d_in[0];   // [2][1024][128]
  const float* k     = (const float*)d_in[1];   // [2][1024][128]
  const float* queue = (const float*)d_in[2];   // [128][65536]
  float* ws  = (float*)d_ws;
  float* qT  = ws + 8192;                       // [2][128][1024]
  float* out = (float*)d_out;

  hipLaunchKernelGGL(zero_ws, dim3(32), dim3(256), 0, stream, ws);
  hipLaunchKernelGGL(transpose_q, dim3(1024), dim3(256), 0, stream, q, qT);

  // queue part: rows = q[0], cols = queue[128][65536]; shared by both views.
  hipLaunchKernelGGL(colreduce, dim3(32, 32), dim3(256), 0, stream,
                     q, queue, KQ, 2048, ws, ws + 1024, 0);
  // intra, view 0: rows = q[0], cols = qT[0] [128][1024], skip diagonal.
  hipLaunchKernelGGL(colreduce, dim3(32, 4), dim3(256), 0, stream,
                     q, qT, NROWS, 256, ws + 2048, ws + 4096, 1);
  // intra, view 1
  hipLaunchKernelGGL(colreduce, dim3(32, 4), dim3(256), 0, stream,
                     q + 131072, qT + 131072, NROWS, 256,
                     ws + 2048 + 1024, ws + 4096 + 1024, 1);

  hipLaunchKernelGGL(loss1_k, dim3(512), dim3(256), 0, stream, q, k, ws + 6144);
  hipLaunchKernelGGL(final_k, dim3(1), dim3(256), 0, stream, ws, out);
}

// Round 2
// 208.682 us; speedup vs baseline: 3.5106x; 3.5106x over previous
//
#include <hip/hip_runtime.h>
#include <hip/hip_bf16.h>

// MoCo loss on MI355X. V=2, N=1024, D=128, K=65536, fp32 in, 2 fp32 scalars out.
// Round 2: bf16 MFMA for the big fused GEMM+exp reductions.
//
// loss1 = (1/(V*N)) * sum_{x,i} (2 - 2*q[x,i]·k[1-x,i])
// loss2 = -(1/(V*N)) * sum_{x,i} num[x,i]/den[x,i]
//   den[x,i] = sum_j exp(-qdq[i,j]) + sum_{j!=i} exp(-intra_x[i,j])
//   num[x,i] = sum_j qdq*exp(-qdq)  + sum_{j!=i} intra*exp(-intra)
//   qdq from q[0] for BOTH views (reference memoization bug preserved).
//
// ws layout (floats):
//   [0,1024)    QS_e    [1024,2048) QS_ce
//   [2048,4096) IS_e[2][1024]   [4096,6144) IS_ce[2][1024]
//   [6144]      l1acc
//   byte 32768+ : Bblk — blocked bf16 queue operand (chunked to fit ws_size)
//
// MFMA fragment layouts (measured, per guide §3):
//   A: A[m = lane&15][k = quad*8 + j]   (8 contiguous k per lane)
//   B: B[k = quad*8 + j][n = lane&15]
//   C: col = lane&15, row = quad*4 + reg

#define NROWS 1024
#define DDIM  128
#define KQ    65536

typedef __attribute__((ext_vector_type(8))) short  short8;
typedef __attribute__((ext_vector_type(4))) float  float4v;

__device__ __forceinline__ unsigned short f2bf(float f) {
  unsigned u = __float_as_uint(f);
  u += 0x7FFF + ((u >> 16) & 1);           // RNE
  return (unsigned short)(u >> 16);
}

__device__ __forceinline__ short8 cvt8(const float* __restrict__ p) {
  float4 a = *(const float4*)p;
  float4 b = *(const float4*)(p + 4);
  short8 r;
  r[0] = (short)f2bf(a.x); r[1] = (short)f2bf(a.y);
  r[2] = (short)f2bf(a.z); r[3] = (short)f2bf(a.w);
  r[4] = (short)f2bf(b.x); r[5] = (short)f2bf(b.y);
  r[6] = (short)f2bf(b.z); r[7] = (short)f2bf(b.w);
  return r;
}

__device__ __forceinline__ float wave_sum(float v) {
  #pragma unroll
  for (int o = 32; o > 0; o >>= 1) v += __shfl_down(v, o, 64);
  return v;
}

__global__ void zero_ws(float* __restrict__ ws) {
  ws[blockIdx.x * 256 + threadIdx.x] = 0.f;
}

// queue [128][65536] fp32  ->  Bblk[jt-jt0][kk][lane][8] bf16
// element = queue[kk*32 + (lane>>4)*8 + t][jt*16 + (lane&15)]
__global__ void conv_B(const float* __restrict__ queue,
                       unsigned short* __restrict__ Bblk, int jt0) {
  const int lane = (int)threadIdx.x & 63;
  const int kk   = (int)threadIdx.x >> 6;          // 0..3
  const int jt   = jt0 + (int)blockIdx.x;
  const int quad = lane >> 4;
  const int col  = jt * 16 + (lane & 15);
  const int dbase = kk * 32 + quad * 8;
  short8 r;
  #pragma unroll
  for (int t = 0; t < 8; ++t)
    r[t] = (short)f2bf(queue[(size_t)(dbase + t) * KQ + col]);
  *(short8*)(Bblk + (((size_t)blockIdx.x * 4 + kk) * 64 + lane) * 8) = r;
}

// Queue part: rows = q[0] (block owns 64 rows), cols = Bblk chunk (cnt tiles of 16).
__global__ __launch_bounds__(256) void mfma_queue(
    const float* __restrict__ q, const unsigned short* __restrict__ Bblk,
    int cnt, float* __restrict__ acc_e, float* __restrict__ acc_ce) {
  const int lane = (int)threadIdx.x & 63;
  const int wave = (int)threadIdx.x >> 6;
  const int quad = lane >> 4;
  const int m    = lane & 15;
  const int rowBase = (int)blockIdx.x * 64;

  short8 a[4][4];
  #pragma unroll
  for (int rg = 0; rg < 4; ++rg)
    #pragma unroll
    for (int kk = 0; kk < 4; ++kk)
      a[rg][kk] = cvt8(q + (size_t)(rowBase + rg * 16 + m) * DDIM + kk * 32 + quad * 8);

  float ae[4][4] = {}, ace[4][4] = {};

  for (int wt = (int)blockIdx.y * 4 + wave; wt < cnt; wt += (int)gridDim.y * 4) {
    short8 b[4];
    const unsigned short* bp = Bblk + (size_t)wt * 2048 + lane * 8;
    #pragma unroll
    for (int kk = 0; kk < 4; ++kk) b[kk] = *(const short8*)(bp + kk * 512);
    #pragma unroll
    for (int rg = 0; rg < 4; ++rg) {
      float4v C = {0.f, 0.f, 0.f, 0.f};
      #pragma unroll
      for (int kk = 0; kk < 4; ++kk)
        C = __builtin_amdgcn_mfma_f32_16x16x32_bf16(a[rg][kk], b[kk], C, 0, 0, 0);
      #pragma unroll
      for (int r = 0; r < 4; ++r) {
        float c = fmaf(-2.f, C[r], 2.f);
        float e = __expf(-c);
        ae[rg][r] += e;
        ace[rg][r] = fmaf(c, e, ace[rg][r]);
      }
    }
  }

  #pragma unroll
  for (int rg = 0; rg < 4; ++rg)
    #pragma unroll
    for (int r = 0; r < 4; ++r) {
      float e = ae[rg][r], ce = ace[rg][r];
      #pragma unroll
      for (int mk = 8; mk >= 1; mk >>= 1) {
        e  += __shfl_xor(e,  mk, 64);
        ce += __shfl_xor(ce, mk, 64);
      }
      if (m == 0) {
        int row = rowBase + rg * 16 + quad * 4 + r;
        atomicAdd(&acc_e[row],  e);
        atomicAdd(&acc_ce[row], ce);
      }
    }
}

// Intra part: A = q[x] rows, B = q[x] rows as columns (both cvt'd in-kernel), diag excluded.
__global__ __launch_bounds__(256) void mfma_intra(
    const float* __restrict__ q, float* __restrict__ acc_e, float* __restrict__ acc_ce) {
  const int x = (int)blockIdx.z;
  const float* qx = q + (size_t)x * NROWS * DDIM;
  const int lane = (int)threadIdx.x & 63;
  const int wave = (int)threadIdx.x >> 6;
  const int quad = lane >> 4;
  const int m    = lane & 15;
  const int rowBase = (int)blockIdx.x * 64;
  const int jt   = (int)blockIdx.y * 4 + wave;
  const int col  = jt * 16 + m;

  short8 b[4];
  #pragma unroll
  for (int kk = 0; kk < 4; ++kk)
    b[kk] = cvt8(qx + (size_t)(jt * 16 + m) * DDIM + kk * 32 + quad * 8);

  float* ae_p  = acc_e  + x * NROWS;
  float* ace_p = acc_ce + x * NROWS;

  #pragma unroll
  for (int rg = 0; rg < 4; ++rg) {
    short8 a[4];
    #pragma unroll
    for (int kk = 0; kk < 4; ++kk)
      a[kk] = cvt8(qx + (size_t)(rowBase + rg * 16 + m) * DDIM + kk * 32 + quad * 8);
    float4v C = {0.f, 0.f, 0.f, 0.f};
    #pragma unroll
    for (int kk = 0; kk < 4; ++kk)
      C = __builtin_amdgcn_mfma_f32_16x16x32_bf16(a[kk], b[kk], C, 0, 0, 0);
    #pragma unroll
    for (int r = 0; r < 4; ++r) {
      int row = rowBase + rg * 16 + quad * 4 + r;
      float c = fmaf(-2.f, C[r], 2.f);
      float e = __expf(-c);
      float ce = c * e;
      if (row == col) { e = 0.f; ce = 0.f; }    // off-diagonal only
      #pragma unroll
      for (int mk = 8; mk >= 1; mk >>= 1) {
        e  += __shfl_xor(e,  mk, 64);
        ce += __shfl_xor(ce, mk, 64);
      }
      if (m == 0) { atomicAdd(&ae_p[row], e); atomicAdd(&ace_p[row], ce); }
    }
  }
}

// loss1: one wave per (x,i); fp32 exact.
__global__ void loss1_k(const float* __restrict__ q, const float* __restrict__ k,
                        float* __restrict__ l1acc) {
  int gw   = (int)(blockIdx.x * blockDim.x + threadIdx.x) >> 6;   // 0..2047
  int lane = (int)threadIdx.x & 63;
  int x = gw >> 10;
  int i = gw & 1023;
  const float2* qp = (const float2*)(q + (size_t)(x * NROWS + i) * DDIM);
  const float2* kp = (const float2*)(k + (size_t)((1 - x) * NROWS + i) * DDIM);
  float2 a = qp[lane];
  float2 b = kp[lane];
  float s = wave_sum(a.x * b.x + a.y * b.y);
  if (lane == 0) atomicAdd(l1acc, (2.f - 2.f * s) * (1.f / (2.f * NROWS)));
}

__global__ void final_k(const float* __restrict__ ws, float* __restrict__ out) {
  const float* QS_e  = ws;
  const float* QS_ce = ws + 1024;
  const float* IS_e  = ws + 2048;
  const float* IS_ce = ws + 4096;
  const float* l1    = ws + 6144;
  __shared__ float red[256];
  float part = 0.f;
  for (int idx = (int)threadIdx.x; idx < 2048; idx += 256) {
    int x = idx >> 10;
    int i = idx & 1023;
    float den = QS_e[i] + IS_e[x * 1024 + i];
    float num = QS_ce[i] + IS_ce[x * 1024 + i];
    part += num / den;
  }
  red[threadIdx.x] = part;
  __syncthreads();
  for (int s = 128; s > 0; s >>= 1) {
    if ((int)threadIdx.x < s) red[threadIdx.x] += red[threadIdx.x + s];
    __syncthreads();
  }
  if (threadIdx.x == 0) {
    out[0] = l1[0];
    out[1] = -red[0] * (1.f / (2.f * NROWS));
  }
}

extern "C" void kernel_launch(void* const* d_in, const int* in_sizes, int n_in,
                              void* d_out, int out_size, void* d_ws, size_t ws_size,
                              hipStream_t stream) {
  const float* q     = (const float*)d_in[0];   // [2][1024][128]
  const float* k     = (const float*)d_in[1];   // [2][1024][128]
  const float* queue = (const float*)d_in[2];   // [128][65536]
  float* ws  = (float*)d_ws;
  float* out = (float*)d_out;
  unsigned short* Bblk = (unsigned short*)((char*)d_ws + 32768);

  // chunk Bblk to fit ws: one jt (16 cols x 128 k bf16) = 4096 bytes
  size_t avail = (ws_size > 32768) ? (ws_size - 32768) : 4096;
  int maxJt = (int)(avail / 4096);
  if (maxJt > 4096) maxJt = 4096;
  if (maxJt < 1) maxJt = 1;
  int nch = (4096 + maxJt - 1) / maxJt;

  hipLaunchKernelGGL(zero_ws, dim3(32), dim3(256), 0, stream, ws);
  hipLaunchKernelGGL(mfma_intra, dim3(16, 16, 2), dim3(256), 0, stream,
                     q, ws + 2048, ws + 4096);
  hipLaunchKernelGGL(loss1_k, dim3(512), dim3(256), 0, stream, q, k, ws + 6144);

  for (int c = 0; c < nch; ++c) {
    int jt0  = c * maxJt;
    int cntc = 4096 - jt0; if (cntc > maxJt) cntc = maxJt;
    hipLaunchKernelGGL(conv_B, dim3(cntc), dim3(256), 0, stream, queue, Bblk, jt0);
    int gy = (cntc + 3) / 4; if (gy > 64) gy = 64;
    hipLaunchKernelGGL(mfma_queue, dim3(16, gy), dim3(256), 0, stream,
                       q, Bblk, cntc, ws, ws + 1024);
  }

  hipLaunchKernelGGL(final_k, dim3(1), dim3(256), 0, stream, ws, out);
}

// Round 3
// 189.638 us; speedup vs baseline: 3.8632x; 1.1004x over previous
//
#include <hip/hip_runtime.h>
#include <hip/hip_bf16.h>

// MoCo loss on MI355X. V=2, N=1024, D=128, K=65536, fp32 in, 2 fp32 scalars out.
// Round 3: prefetched MFMA main loop, cheap exp2 epilogue, coalesced conv.
//
// loss2 row sums: acc_e[i] += exp(-c), acc_ce[i] += c*exp(-c), c = 2-2*dot.
// We accumulate Se = sum e and Sde = sum d*e; then sum c*e = 2*(Se - Sde).
//
// ws floats: [0,1024) QS_e | [1024,2048) QS_ce | [2048,4096) IS_e[2][1024]
//            [4096,6144) IS_ce[2][1024] | [6144] l1acc | byte 32768+: Bblk (bf16)
//
// MFMA 16x16x32 bf16 layouts: A[m=lane&15][k=quad*8+j]; B[k=quad*8+j][n=lane&15];
// C: col=lane&15, row=quad*4+reg.

#define NROWS 1024
#define DDIM  128
#define KQ    65536
#define TWO_LOG2E 2.8853900817779268f

typedef __attribute__((ext_vector_type(8))) short  short8;
typedef __attribute__((ext_vector_type(4))) float  float4v;

#if __has_builtin(__builtin_amdgcn_exp2f)
#define EXP2(x) __builtin_amdgcn_exp2f(x)
#else
#define EXP2(x) __expf((x) * 0.6931471805599453f)
#endif

__device__ __forceinline__ unsigned short f2bf(float f) {
  unsigned u = __float_as_uint(f);
  u += 0x7FFF + ((u >> 16) & 1);           // RNE
  return (unsigned short)(u >> 16);
}

__device__ __forceinline__ short8 cvt8(const float* __restrict__ p) {
  float4 a = *(const float4*)p;
  float4 b = *(const float4*)(p + 4);
  short8 r;
  r[0] = (short)f2bf(a.x); r[1] = (short)f2bf(a.y);
  r[2] = (short)f2bf(a.z); r[3] = (short)f2bf(a.w);
  r[4] = (short)f2bf(b.x); r[5] = (short)f2bf(b.y);
  r[6] = (short)f2bf(b.z); r[7] = (short)f2bf(b.w);
  return r;
}

__device__ __forceinline__ float wave_sum(float v) {
  #pragma unroll
  for (int o = 32; o > 0; o >>= 1) v += __shfl_down(v, o, 64);
  return v;
}

__global__ void zero_ws(float* __restrict__ ws) {
  ws[blockIdx.x * 256 + threadIdx.x] = 0.f;
}

// queue [128][65536] fp32 -> Bblk[tile][kk][quad*16+n][j] bf16 (tile = 4KB).
// Block: 64 cols x 128 d. Thread: g=tid>>4 -> d0=g*8 (kk=g>>2, quad=g&3);
// ci=(tid&15)*4 -> 4 cols. Reads: 4x256B segments/instr. Writes: 64B/thread.
__global__ void conv_B(const float* __restrict__ queue,
                       unsigned short* __restrict__ Bblk, int c0chunk) {
  const int tid  = (int)threadIdx.x;
  const int g    = tid >> 4;
  const int ci   = (tid & 15) * 4;
  const int cloc = (int)blockIdx.x * 64 + ci;     // chunk-local col
  const int c    = c0chunk + cloc;                // global col
  const int d0   = g * 8;
  const int kk   = g >> 2;
  const int quad = g & 3;

  float4 v[8];
  #pragma unroll
  for (int dd = 0; dd < 8; ++dd)
    v[dd] = *(const float4*)(queue + (size_t)(d0 + dd) * KQ + c);

  unsigned short* outp = Bblk + ((size_t)(cloc >> 4) * 4 + kk) * 512
                              + (quad * 16 + (cloc & 15)) * 8;
  #pragma unroll
  for (int n = 0; n < 4; ++n) {
    short8 s;
    #pragma unroll
    for (int dd = 0; dd < 8; ++dd)
      s[dd] = (short)f2bf(((const float*)&v[dd])[n]);
    *(short8*)(outp + n * 8) = s;
  }
}

// Queue part: block owns 64 rows of q[0]; waves stride over col tiles with
// register-double-buffered B.
__global__ __launch_bounds__(256) void mfma_queue(
    const float* __restrict__ q, const unsigned short* __restrict__ Bblk,
    int cnt, float* __restrict__ acc_e, float* __restrict__ acc_ce) {
  const int lane = (int)threadIdx.x & 63;
  const int wave = (int)threadIdx.x >> 6;
  const int quad = lane >> 4;
  const int m    = lane & 15;
  const int rowBase = (int)blockIdx.x * 64;

  short8 a[4][4];
  #pragma unroll
  for (int rg = 0; rg < 4; ++rg)
    #pragma unroll
    for (int kk = 0; kk < 4; ++kk)
      a[rg][kk] = cvt8(q + (size_t)(rowBase + rg * 16 + m) * DDIM + kk * 32 + quad * 8);

  float ae[4][4] = {}, ade[4][4] = {};

  const int stride = (int)gridDim.y * 4;
  int wt = (int)blockIdx.y * 4 + wave;
  if (wt < cnt) {
    short8 bc[4];
    {
      const unsigned short* bp = Bblk + (size_t)wt * 2048 + lane * 8;
      #pragma unroll
      for (int kk = 0; kk < 4; ++kk) bc[kk] = *(const short8*)(bp + kk * 512);
    }
    while (true) {
      const int wtn = wt + stride;
      const bool more = wtn < cnt;
      short8 bn[4];
      if (more) {
        const unsigned short* bp = Bblk + (size_t)wtn * 2048 + lane * 8;
        #pragma unroll
        for (int kk = 0; kk < 4; ++kk) bn[kk] = *(const short8*)(bp + kk * 512);
      }
      #pragma unroll
      for (int rg = 0; rg < 4; ++rg) {
        float4v C = {0.f, 0.f, 0.f, 0.f};
        #pragma unroll
        for (int kk = 0; kk < 4; ++kk)
          C = __builtin_amdgcn_mfma_f32_16x16x32_bf16(a[rg][kk], bc[kk], C, 0, 0, 0);
        #pragma unroll
        for (int r = 0; r < 4; ++r) {
          float d = C[r];
          float e = EXP2(fmaf(d, TWO_LOG2E, -TWO_LOG2E));
          ae[rg][r] += e;
          ade[rg][r] = fmaf(d, e, ade[rg][r]);
        }
      }
      if (!more) break;
      wt = wtn;
      #pragma unroll
      for (int kk = 0; kk < 4; ++kk) bc[kk] = bn[kk];
    }
  }

  #pragma unroll
  for (int rg = 0; rg < 4; ++rg)
    #pragma unroll
    for (int r = 0; r < 4; ++r) {
      float e = ae[rg][r], de = ade[rg][r];
      #pragma unroll
      for (int mk = 8; mk >= 1; mk >>= 1) {
        e  += __shfl_xor(e,  mk, 64);
        de += __shfl_xor(de, mk, 64);
      }
      if (m == 0) {
        int row = rowBase + rg * 16 + quad * 4 + r;
        atomicAdd(&acc_e[row],  e);
        atomicAdd(&acc_ce[row], 2.f * (e - de));
      }
    }
}

// Intra part: same structure, B converted from q[x] rows, diagonal masked.
__global__ __launch_bounds__(256) void mfma_intra(
    const float* __restrict__ q, float* __restrict__ acc_e, float* __restrict__ acc_ce) {
  const int x = (int)blockIdx.z;
  const float* qx = q + (size_t)x * NROWS * DDIM;
  const int lane = (int)threadIdx.x & 63;
  const int wave = (int)threadIdx.x >> 6;
  const int quad = lane >> 4;
  const int m    = lane & 15;
  const int rowBase = (int)blockIdx.x * 64;

  short8 a[4][4];
  #pragma unroll
  for (int rg = 0; rg < 4; ++rg)
    #pragma unroll
    for (int kk = 0; kk < 4; ++kk)
      a[rg][kk] = cvt8(qx + (size_t)(rowBase + rg * 16 + m) * DDIM + kk * 32 + quad * 8);

  float ae[4][4] = {}, ade[4][4] = {};

  for (int jt = (int)blockIdx.y * 4 + wave; jt < NROWS / 16; jt += (int)gridDim.y * 4) {
    short8 b[4];
    #pragma unroll
    for (int kk = 0; kk < 4; ++kk)
      b[kk] = cvt8(qx + (size_t)(jt * 16 + m) * DDIM + kk * 32 + quad * 8);
    const int dgRg = (jt * 16 - rowBase) >> 4;   // 0..3 iff this tile hits the diagonal
    #pragma unroll
    for (int rg = 0; rg < 4; ++rg) {
      float4v C = {0.f, 0.f, 0.f, 0.f};
      #pragma unroll
      for (int kk = 0; kk < 4; ++kk)
        C = __builtin_amdgcn_mfma_f32_16x16x32_bf16(a[rg][kk], b[kk], C, 0, 0, 0);
      #pragma unroll
      for (int r = 0; r < 4; ++r) {
        float d = C[r];
        float e = EXP2(fmaf(d, TWO_LOG2E, -TWO_LOG2E));
        float de = d * e;
        if (rg == dgRg && (quad * 4 + r) == m) { e = 0.f; de = 0.f; }  // exclude diag
        ae[rg][r] += e;
        ade[rg][r] += de;
      }
    }
  }

  #pragma unroll
  for (int rg = 0; rg < 4; ++rg)
    #pragma unroll
    for (int r = 0; r < 4; ++r) {
      float e = ae[rg][r], de = ade[rg][r];
      #pragma unroll
      for (int mk = 8; mk >= 1; mk >>= 1) {
        e  += __shfl_xor(e,  mk, 64);
        de += __shfl_xor(de, mk, 64);
      }
      if (m == 0) {
        int row = rowBase + rg * 16 + quad * 4 + r;
        atomicAdd(&acc_e[x * NROWS + row],  e);
        atomicAdd(&acc_ce[x * NROWS + row], 2.f * (e - de));
      }
    }
}

// loss1: one wave per (x,i); fp32 exact.
__global__ void loss1_k(const float* __restrict__ q, const float* __restrict__ k,
                        float* __restrict__ l1acc) {
  int gw   = (int)(blockIdx.x * blockDim.x + threadIdx.x) >> 6;   // 0..2047
  int lane = (int)threadIdx.x & 63;
  int x = gw >> 10;
  int i = gw & 1023;
  const float2* qp = (const float2*)(q + (size_t)(x * NROWS + i) * DDIM);
  const float2* kp = (const float2*)(k + (size_t)((1 - x) * NROWS + i) * DDIM);
  float2 a = qp[lane];
  float2 b = kp[lane];
  float s = wave_sum(a.x * b.x + a.y * b.y);
  if (lane == 0) atomicAdd(l1acc, (2.f - 2.f * s) * (1.f / (2.f * NROWS)));
}

__global__ void final_k(const float* __restrict__ ws, float* __restrict__ out) {
  const float* QS_e  = ws;
  const float* QS_ce = ws + 1024;
  const float* IS_e  = ws + 2048;
  const float* IS_ce = ws + 4096;
  const float* l1    = ws + 6144;
  __shared__ float red[256];
  float part = 0.f;
  for (int idx = (int)threadIdx.x; idx < 2048; idx += 256) {
    int x = idx >> 10;
    int i = idx & 1023;
    float den = QS_e[i] + IS_e[x * 1024 + i];
    float num = QS_ce[i] + IS_ce[x * 1024 + i];
    part += num / den;
  }
  red[threadIdx.x] = part;
  __syncthreads();
  for (int s = 128; s > 0; s >>= 1) {
    if ((int)threadIdx.x < s) red[threadIdx.x] += red[threadIdx.x + s];
    __syncthreads();
  }
  if (threadIdx.x == 0) {
    out[0] = l1[0];
    out[1] = -red[0] * (1.f / (2.f * NROWS));
  }
}

extern "C" void kernel_launch(void* const* d_in, const int* in_sizes, int n_in,
                              void* d_out, int out_size, void* d_ws, size_t ws_size,
                              hipStream_t stream) {
  const float* q     = (const float*)d_in[0];   // [2][1024][128]
  const float* k     = (const float*)d_in[1];   // [2][1024][128]
  const float* queue = (const float*)d_in[2];   // [128][65536]
  float* ws  = (float*)d_ws;
  float* out = (float*)d_out;
  unsigned short* Bblk = (unsigned short*)((char*)d_ws + 32768);

  // Chunk Bblk to fit ws: one col-tile (16 cols x 128 k bf16) = 4096 bytes.
  size_t avail = (ws_size > 32768) ? (ws_size - 32768) : 16384;
  int maxJt = (int)(avail / 4096);
  maxJt &= ~3;                       // conv_B block covers 4 tiles
  if (maxJt > 4096) maxJt = 4096;
  if (maxJt < 4) maxJt = 4;
  int nch = (4096 + maxJt - 1) / maxJt;

  hipLaunchKernelGGL(zero_ws, dim3(32), dim3(256), 0, stream, ws);
  hipLaunchKernelGGL(mfma_intra, dim3(16, 8, 2), dim3(256), 0, stream,
                     q, ws + 2048, ws + 4096);
  hipLaunchKernelGGL(loss1_k, dim3(512), dim3(256), 0, stream, q, k, ws + 6144);

  for (int c = 0; c < nch; ++c) {
    int jt0  = c * maxJt;
    int cntc = 4096 - jt0; if (cntc > maxJt) cntc = maxJt;
    hipLaunchKernelGGL(conv_B, dim3(cntc / 4), dim3(256), 0, stream,
                       queue, Bblk, jt0 * 16);
    int gy = (cntc + 3) / 4; if (gy > 64) gy = 64;
    hipLaunchKernelGGL(mfma_queue, dim3(16, gy), dim3(256), 0, stream,
                       q, Bblk, cntc, ws, ws + 1024);
  }

  hipLaunchKernelGGL(final_k, dim3(1), dim3(256), 0, stream, ws, out);
}